// Round 2
// baseline (8239.613 us; speedup 1.0000x reference)
//
#include <hip/hip_runtime.h>
#include <math.h>

typedef __bf16 bf16_t;
typedef bf16_t bf16x8 __attribute__((ext_vector_type(8)));
typedef bf16_t bf16x4 __attribute__((ext_vector_type(4)));
typedef float  f32x4  __attribute__((ext_vector_type(4)));

#define NB 32      // batch
#define NN 512     // nodes
#define NH 64      // hidden
#define NF 384     // NUM_MATS * CONCAT
#define FP 392     // feat LDS row stride (elements, padded)

static __device__ __forceinline__ f32x4 mfma16(bf16x8 a, bf16x8 b, f32x4 c){
  return __builtin_amdgcn_mfma_f32_16x16x32_bf16(a, b, c, 0, 0, 0);
}

// ---------------- setup kernels ----------------------------------------------------
__global__ __launch_bounds__(256) void k_convert_S(const float* __restrict__ S,
                                                   bf16_t* __restrict__ Sb){
  int i = blockIdx.x * 256 + threadIdx.x;
  f32x4 v = *(const f32x4*)&S[(size_t)i * 4];
  bf16x4 o;
  #pragma unroll
  for (int q = 0; q < 4; ++q) o[q] = (bf16_t)v[q];
  *(bf16x4*)&Sb[(size_t)i * 4] = o;
}

// S2 = S @ S in f32 (exact), stored bf16.  grid 1024 x 256
__global__ __launch_bounds__(256) void k_s2(const float* __restrict__ S,
                                            bf16_t* __restrict__ S2b){
  int idx = blockIdx.x * 256 + threadIdx.x;    // 262144 = 512*512
  int n = idx >> 9, m = idx & 511;
  float acc = 0.f;
  for (int k = 0; k < 512; ++k) acc += S[n * 512 + k] * S[k * 512 + m];
  S2b[idx] = (bf16_t)acc;
}

__global__ __launch_bounds__(256) void k_transW(const float* __restrict__ W,
                                                bf16_t* __restrict__ Wt, int OD){
  int i = blockIdx.x * 256 + threadIdx.x;
  int total = 2 * NF * OD;
  if (i >= total) return;
  int l = i / (NF * OD), rem = i - l * (NF * OD);
  int o = rem / NF, f = rem - o * NF;
  Wt[i] = (bf16_t)W[(size_t)(l * NF + f) * OD + o];
}

// h0[l] (f32 [b][n][o]) -> hTf (f32 [b][o][n]) + hTb (bf16 same) + hNb (bf16 [b][n][o])
__global__ __launch_bounds__(256) void k_hinit(const float* __restrict__ h0l,
                                               float* __restrict__ hTf,
                                               bf16_t* __restrict__ hTb,
                                               bf16_t* __restrict__ hNb){
  __shared__ float tile[64 * 65];
  const int n0 = blockIdx.x * 64, b = blockIdx.y, tid = threadIdx.x;
  const float* src = h0l + ((size_t)b * NN + n0) * NH;
  #pragma unroll
  for (int s = 0; s < 4; ++s){
    int i = tid + s * 256;
    int r = i >> 4, c4 = (i & 15) * 4;
    f32x4 v = *(const f32x4*)&src[(size_t)r * NH + c4];
    bf16x4 bv;
    #pragma unroll
    for (int q = 0; q < 4; ++q) bv[q] = (bf16_t)v[q];
    *(bf16x4*)&hNb[((size_t)b * NN + n0 + r) * NH + c4] = bv;
    #pragma unroll
    for (int q = 0; q < 4; ++q) tile[(c4 + q) * 65 + r] = v[q];
  }
  __syncthreads();
  #pragma unroll
  for (int s = 0; s < 4; ++s){
    int i = tid + s * 256;
    int o = i >> 4, c4 = (i & 15) * 4;
    f32x4 v;
    #pragma unroll
    for (int q = 0; q < 4; ++q) v[q] = tile[o * 65 + c4 + q];
    *(f32x4*)&hTf[((size_t)b * NH + o) * NN + n0 + c4] = v;
    bf16x4 bv;
    #pragma unroll
    for (int q = 0; q < 4; ++q) bv[q] = (bf16_t)v[q];
    *(bf16x4*)&hTb[((size_t)b * NH + o) * NN + n0 + c4] = bv;
  }
}

// per-step: x (f32 [b][n][64]) -> xT (bf16 [b][64][512])
__global__ __launch_bounds__(256) void k_xt(const float* __restrict__ x,
                                            bf16_t* __restrict__ xT){
  __shared__ float tile[64 * 65];
  const int n0 = blockIdx.x * 64, b = blockIdx.y, tid = threadIdx.x;
  const float* src = x + ((size_t)b * NN + n0) * NH;
  #pragma unroll
  for (int s = 0; s < 4; ++s){
    int i = tid + s * 256;
    int r = i >> 4, c4 = (i & 15) * 4;
    f32x4 v = *(const f32x4*)&src[(size_t)r * NH + c4];
    #pragma unroll
    for (int q = 0; q < 4; ++q) tile[(c4 + q) * 65 + r] = v[q];
  }
  __syncthreads();
  #pragma unroll
  for (int s = 0; s < 4; ++s){
    int i = tid + s * 256;
    int o = i >> 4, c4 = (i & 15) * 4;
    bf16x4 bv;
    #pragma unroll
    for (int q = 0; q < 4; ++q) bv[q] = (bf16_t)tile[o * 65 + c4 + q];
    *(bf16x4*)&xT[((size_t)b * NH + o) * NN + n0 + c4] = bv;
  }
}

// generic f32 64x64-tile transpose (final hidden output)
__global__ __launch_bounds__(256) void k_transpose_f32(const float* __restrict__ src,
                                                       float* __restrict__ dst,
                                                       int src_ld, int dst_ld,
                                                       long src_bs, long dst_bs){
  __shared__ float tile[64 * 65];
  const float* s = src + blockIdx.z * src_bs + (size_t)(blockIdx.x * 64) * src_ld + blockIdx.y * 64;
  float* d = dst + blockIdx.z * dst_bs + (size_t)(blockIdx.y * 64) * dst_ld + blockIdx.x * 64;
  for (int i = threadIdx.x; i < 4096; i += 256){
    int r = i >> 6, c = i & 63;
    tile[c * 65 + r] = s[(size_t)r * src_ld + c];
  }
  __syncthreads();
  for (int i = threadIdx.x; i < 4096; i += 256){
    int r = i >> 6, c = i & 63;
    d[(size_t)r * dst_ld + c] = tile[r * 65 + c];
  }
}

// ---------------- fused gate kernel ------------------------------------------------
// block: 32 n-rows x b. waves 0-3: t1 = S@xh (c 0-127); waves 4-7: S2@xh -> t2.
// then dense gatesT[o 128][n 32] = WgT @ feat^T, sigmoid, u -> uT, rh -> rhT/rhN.
__global__ __launch_bounds__(512) void k_gate(
    const float* __restrict__ x, const bf16_t* __restrict__ xT,
    const bf16_t* __restrict__ hTb, const bf16_t* __restrict__ hNb,
    const float* __restrict__ hTf,
    const bf16_t* __restrict__ Sb, const bf16_t* __restrict__ S2b,
    const bf16_t* __restrict__ Wg, const float* __restrict__ bg,
    bf16_t* __restrict__ rhT, bf16_t* __restrict__ rhN,
    float* __restrict__ uT,
    bf16_t* __restrict__ t1x, bf16_t* __restrict__ t2x)
{
  __shared__ union {
    bf16_t feat[32 * FP];
    struct { bf16_t rhL[64 * 40]; float uL[64 * 36]; } e;
  } sm;
  const int n0 = blockIdx.x * 32, b = blockIdx.y;
  const int tid = threadIdx.x, lane = tid & 63, w = tid >> 6;
  const int fr = lane & 15, ko = (lane >> 4) * 8, ro = (lane >> 4) * 4;

  // phase 0: xh -> feat cols 0..127
  {
    int r = tid >> 4, c4 = (tid & 15) * 4;
    f32x4 v = *(const f32x4*)&x[((size_t)b * NN + n0 + r) * NH + c4];
    bf16x4 bv;
    #pragma unroll
    for (int q = 0; q < 4; ++q) bv[q] = (bf16_t)v[q];
    *(bf16x4*)&sm.feat[r * FP + c4] = bv;
    if (tid < 256){
      int r2 = tid >> 3, c8 = (tid & 7) * 8;
      *(bf16x8*)&sm.feat[r2 * FP + 64 + c8] =
          *(const bf16x8*)&hNb[((size_t)b * NN + n0 + r2) * NH + c8];
    }
  }
  __syncthreads();

  // phase 1: diffusion matmuls, fragments direct from global (L2-resident)
  {
    const int grp = w >> 2, sub = w & 3, c0 = sub * 32;
    const bf16_t* A = grp ? S2b : Sb;
    const bf16_t* Bp[2];
    #pragma unroll
    for (int bn = 0; bn < 2; ++bn){
      int c = c0 + bn * 16 + fr;
      Bp[bn] = (c < 64) ? (xT + ((size_t)b * NH + c) * NN)
                        : (hTb + ((size_t)b * NH + (c - 64)) * NN);
    }
    const bf16_t* Ap0 = A + (size_t)(n0 + fr) * NN;
    const bf16_t* Ap1 = A + (size_t)(n0 + 16 + fr) * NN;
    f32x4 acc[2][2] = {};
    for (int kt = 0; kt < 16; ++kt){
      int k0 = kt * 32 + ko;
      bf16x8 a0 = *(const bf16x8*)&Ap0[k0];
      bf16x8 a1 = *(const bf16x8*)&Ap1[k0];
      bf16x8 b0 = *(const bf16x8*)&Bp[0][k0];
      bf16x8 b1 = *(const bf16x8*)&Bp[1][k0];
      acc[0][0] = mfma16(a0, b0, acc[0][0]);
      acc[0][1] = mfma16(a0, b1, acc[0][1]);
      acc[1][0] = mfma16(a1, b0, acc[1][0]);
      acc[1][1] = mfma16(a1, b1, acc[1][1]);
    }
    #pragma unroll
    for (int ar = 0; ar < 2; ++ar)
      #pragma unroll
      for (int bn = 0; bn < 2; ++bn)
        #pragma unroll
        for (int r = 0; r < 4; ++r){
          int nl = ar * 16 + ro + r;
          int c  = c0 + bn * 16 + fr;
          if (grp == 0) sm.feat[nl * FP + 128 + c] = (bf16_t)acc[ar][bn][r];
          else {
            float xh = (float)sm.feat[nl * FP + c];
            sm.feat[nl * FP + 256 + c] = (bf16_t)(2.f * acc[ar][bn][r] - xh);
          }
        }
  }
  __syncthreads();

  // phase 2a: dump x-halves of t1/t2 for the candidate kernel
  {
    int i = tid & 255;
    int r = i >> 3, c8 = (i & 7) * 8;
    bf16_t* dst = (tid < 256) ? t1x : t2x;
    int base = (tid < 256) ? 128 : 256;
    *(bf16x8*)&dst[((size_t)b * NN + n0 + r) * NH + c8] =
        *(const bf16x8*)&sm.feat[r * FP + base + c8];
  }
  // phase 2b: dense K=384 -> gatesT [o 128][n 32]
  f32x4 dacc[2] = {};
  const int wo = w >> 1, wn = w & 1, o0 = wo * 32, nl0 = wn * 16;
  {
    const bf16_t* Aw0 = Wg + (size_t)(o0 + fr) * NF;
    const bf16_t* Aw1 = Wg + (size_t)(o0 + 16 + fr) * NF;
    const bf16_t* Bl = &sm.feat[(nl0 + fr) * FP];
    for (int kt = 0; kt < 12; ++kt){
      int k0 = kt * 32 + ko;
      bf16x8 bfr = *(const bf16x8*)&Bl[k0];
      dacc[0] = mfma16(*(const bf16x8*)&Aw0[k0], bfr, dacc[0]);
      dacc[1] = mfma16(*(const bf16x8*)&Aw1[k0], bfr, dacc[1]);
    }
  }
  __syncthreads();   // feat no longer needed; LDS becomes e.*
  // epilogue: sigmoid; r*h and u into LDS
  {
    #pragma unroll
    for (int ao = 0; ao < 2; ++ao)
      #pragma unroll
      for (int r = 0; r < 4; ++r){
        int o = o0 + ao * 16 + ro + r;
        int nl = nl0 + fr;
        float g = 1.f / (1.f + __expf(-(dacc[ao][r] + bg[o])));
        if (o < 64){
          float h = hTf[((size_t)b * NH + o) * NN + n0 + nl];
          sm.e.rhL[o * 40 + nl] = (bf16_t)(g * h);
        } else {
          sm.e.uL[(o - 64) * 36 + nl] = g;
        }
      }
  }
  __syncthreads();
  // phase 3: coalesced dumps
  {
    if (tid < 256){
      int o = tid >> 2, c8 = (tid & 3) * 8;
      bf16x8 v;
      #pragma unroll
      for (int q = 0; q < 8; ++q) v[q] = sm.e.rhL[o * 40 + c8 + q];
      *(bf16x8*)&rhT[((size_t)b * NH + o) * NN + n0 + c8] = v;
    } else {
      int i = tid - 256;
      int n = i >> 3, o8 = (i & 7) * 8;
      bf16x8 v;
      #pragma unroll
      for (int q = 0; q < 8; ++q) v[q] = sm.e.rhL[(o8 + q) * 40 + n];
      *(bf16x8*)&rhN[((size_t)b * NN + n0 + n) * NH + o8] = v;
    }
    int o = tid >> 3, c4 = (tid & 7) * 4;
    f32x4 v;
    #pragma unroll
    for (int q = 0; q < 4; ++q) v[q] = sm.e.uL[o * 36 + c4 + q];
    *(f32x4*)&uT[((size_t)b * NH + o) * NN + n0 + c4] = v;
  }
}

// ---------------- fused candidate kernel -------------------------------------------
__global__ __launch_bounds__(512) void k_cand(
    const float* __restrict__ x,
    const bf16_t* __restrict__ rhT, const bf16_t* __restrict__ rhN,
    const bf16_t* __restrict__ t1x, const bf16_t* __restrict__ t2x,
    const float* __restrict__ uT, float* __restrict__ hTf,
    bf16_t* __restrict__ hTb, bf16_t* __restrict__ hNb,
    const bf16_t* __restrict__ Sb, const bf16_t* __restrict__ S2b,
    const bf16_t* __restrict__ Wc, const float* __restrict__ bc,
    float* __restrict__ cur)
{
  __shared__ union {
    bf16_t feat[32 * FP];
    float nhL[64 * 36];
  } sm;
  const int n0 = blockIdx.x * 32, b = blockIdx.y;
  const int tid = threadIdx.x, lane = tid & 63, w = tid >> 6;
  const int fr = lane & 15, ko = (lane >> 4) * 8, ro = (lane >> 4) * 4;

  // phase 0: feat cols 0-63 (x), 64-127 (rh), 128-191 (t1x), 256-319 (t2x)
  {
    int r = tid >> 4, c4 = (tid & 15) * 4;
    f32x4 v = *(const f32x4*)&x[((size_t)b * NN + n0 + r) * NH + c4];
    bf16x4 bv;
    #pragma unroll
    for (int q = 0; q < 4; ++q) bv[q] = (bf16_t)v[q];
    *(bf16x4*)&sm.feat[r * FP + c4] = bv;
    int r2 = (tid & 255) >> 3, c8 = (tid & 7) * 8;
    const bf16_t* src1 = (tid < 256) ? rhN : t1x;
    int base1 = (tid < 256) ? 64 : 128;
    *(bf16x8*)&sm.feat[r2 * FP + base1 + c8] =
        *(const bf16x8*)&src1[((size_t)b * NN + n0 + r2) * NH + c8];
    if (tid < 256)
      *(bf16x8*)&sm.feat[r2 * FP + 256 + c8] =
          *(const bf16x8*)&t2x[((size_t)b * NN + n0 + r2) * NH + c8];
  }
  __syncthreads();

  // phase 1: t1r = S@rh (grp0, ->192+), t2r = 2*S2@rh - rh (grp1, ->320+)
  {
    const int grp = w >> 2, sub = w & 3, c0 = sub * 16;
    const bf16_t* A = grp ? S2b : Sb;
    int c = c0 + fr;
    const bf16_t* Bp = rhT + ((size_t)b * NH + c) * NN;
    const bf16_t* Ap0 = A + (size_t)(n0 + fr) * NN;
    const bf16_t* Ap1 = A + (size_t)(n0 + 16 + fr) * NN;
    f32x4 acc[2] = {};
    for (int kt = 0; kt < 16; ++kt){
      int k0 = kt * 32 + ko;
      bf16x8 bfr = *(const bf16x8*)&Bp[k0];
      acc[0] = mfma16(*(const bf16x8*)&Ap0[k0], bfr, acc[0]);
      acc[1] = mfma16(*(const bf16x8*)&Ap1[k0], bfr, acc[1]);
    }
    #pragma unroll
    for (int ar = 0; ar < 2; ++ar)
      #pragma unroll
      for (int r = 0; r < 4; ++r){
        int nl = ar * 16 + ro + r;
        if (grp == 0) sm.feat[nl * FP + 192 + c] = (bf16_t)acc[ar][r];
        else {
          float rh = (float)sm.feat[nl * FP + 64 + c];
          sm.feat[nl * FP + 320 + c] = (bf16_t)(2.f * acc[ar][r] - rh);
        }
      }
  }
  __syncthreads();

  // phase 2: dense K=384 -> cT [o 64][n 32]
  f32x4 dacc = {};
  const int wo = w >> 1, wn = w & 1, o0 = wo * 16, nl0 = wn * 16;
  {
    const bf16_t* Aw = Wc + (size_t)(o0 + fr) * NF;
    const bf16_t* Bl = &sm.feat[(nl0 + fr) * FP];
    for (int kt = 0; kt < 12; ++kt){
      int k0 = kt * 32 + ko;
      dacc = mfma16(*(const bf16x8*)&Aw[k0], *(const bf16x8*)&Bl[k0], dacc);
    }
  }
  __syncthreads();
  // epilogue: tanh + GRU update -> nhL
  {
    #pragma unroll
    for (int r = 0; r < 4; ++r){
      int o = o0 + ro + r;
      int nl = nl0 + fr;
      size_t idx = ((size_t)b * NH + o) * NN + n0 + nl;
      float c = tanhf(dacc[r] + bc[o]);
      float u = uT[idx], h = hTf[idx];
      sm.nhL[o * 36 + nl] = u * h + (1.f - u) * c;
    }
  }
  __syncthreads();
  // phase 3: dumps (hTf/hTb rows, cur + hNb transposed)
  {
    int o = tid >> 3, c4 = (tid & 7) * 4;
    f32x4 v;
    #pragma unroll
    for (int q = 0; q < 4; ++q) v[q] = sm.nhL[o * 36 + c4 + q];
    *(f32x4*)&hTf[((size_t)b * NH + o) * NN + n0 + c4] = v;
    bf16x4 bv;
    #pragma unroll
    for (int q = 0; q < 4; ++q) bv[q] = (bf16_t)v[q];
    *(bf16x4*)&hTb[((size_t)b * NH + o) * NN + n0 + c4] = bv;

    int n = tid >> 4, o4 = (tid & 15) * 4;
    f32x4 t;
    #pragma unroll
    for (int q = 0; q < 4; ++q) t[q] = sm.nhL[(o4 + q) * 36 + n];
    *(f32x4*)&cur[((size_t)b * NN + n0 + n) * NH + o4] = t;

    if (tid < 256){
      int n2 = tid >> 3, o8 = (tid & 7) * 8;
      bf16x8 hb;
      #pragma unroll
      for (int q = 0; q < 8; ++q) hb[q] = (bf16_t)sm.nhL[(o8 + q) * 36 + n2];
      *(bf16x8*)&hNb[((size_t)b * NN + n0 + n2) * NH + o8] = hb;
    }
  }
}

// ---------------- host orchestration ----------------------------------------------
extern "C" void kernel_launch(void* const* d_in, const int* in_sizes, int n_in,
                              void* d_out, int out_size, void* d_ws, size_t ws_size,
                              hipStream_t stream){
  const float* inputs = (const float*)d_in[0];
  const float* h0     = (const float*)d_in[1];
  const float* S      = (const float*)d_in[2];
  const float* W_gate = (const float*)d_in[3];
  const float* b_gate = (const float*)d_in[4];
  const float* W_c    = (const float*)d_in[5];
  const float* b_c    = (const float*)d_in[6];
  float* out = (float*)d_out;
  char* ws = (char*)d_ws;

  bf16_t* Sb  = (bf16_t*)(ws + 0);          // 512*512*2      = 524288
  bf16_t* S2b = (bf16_t*)(ws + 524288);     // 524288
  bf16_t* WgT = (bf16_t*)(ws + 1048576);    // 2*128*384*2    = 196608
  bf16_t* WcT = (bf16_t*)(ws + 1245184);    // 2*64*384*2     = 98304
  bf16_t* xT  = (bf16_t*)(ws + 1343488);    // 32*64*512*2    = 2097152
  float*  hTf = (float*) (ws + 3440640);    // 32*64*512*4    = 4194304
  bf16_t* hTb = (bf16_t*)(ws + 7634944);    // 2097152
  bf16_t* hNb = (bf16_t*)(ws + 9732096);    // 2097152
  bf16_t* rhT = (bf16_t*)(ws + 11829248);   // 2097152
  bf16_t* rhN = (bf16_t*)(ws + 13926400);   // 2097152
  float*  uT  = (float*) (ws + 16023552);   // 4194304
  bf16_t* t1x = (bf16_t*)(ws + 20217856);   // 2097152
  bf16_t* t2x = (bf16_t*)(ws + 22315008);   // 2097152 -> end 24412160

  float* finalh = out;                                 // [2][B][N*H]
  float* cur    = out + (size_t)2 * NB * NN * NH;      // [T][B][N*H]

  k_convert_S<<<dim3(256), 256, 0, stream>>>(S, Sb);
  k_s2<<<dim3(1024), 256, 0, stream>>>(S, S2b);
  k_transW<<<dim3((2 * NF * 128 + 255) / 256), 256, 0, stream>>>(W_gate, WgT, 128);
  k_transW<<<dim3((2 * NF * 64 + 255) / 256), 256, 0, stream>>>(W_c, WcT, 64);

  for (int l = 0; l < 2; ++l){
    k_hinit<<<dim3(8, 32), 256, 0, stream>>>(h0 + (size_t)l * NB * NN * NH, hTf, hTb, hNb);
    for (int t = 0; t < 48; ++t){
      const float* xs = (l == 0) ? inputs + (size_t)t * NB * NN * NH
                                 : cur    + (size_t)t * NB * NN * NH;
      k_xt<<<dim3(8, 32), 256, 0, stream>>>(xs, xT);
      k_gate<<<dim3(16, 32), 512, 0, stream>>>(xs, xT, hTb, hNb, hTf, Sb, S2b,
          WgT + (size_t)l * 128 * NF, b_gate + l * 128, rhT, rhN, uT, t1x, t2x);
      k_cand<<<dim3(16, 32), 512, 0, stream>>>(xs, rhT, rhN, t1x, t2x, uT, hTf,
          hTb, hNb, Sb, S2b, WcT + (size_t)l * 64 * NF, b_c + l * 64,
          cur + (size_t)t * NB * NN * NH);
    }
    k_transpose_f32<<<dim3(1, 8, 32), 256, 0, stream>>>(
        hTf, finalh + (size_t)l * NB * NN * NH, NN, NH,
        (long)NH * NN, (long)NN * NH);
  }
}